// Round 1
// baseline (1389.570 us; speedup 1.0000x reference)
//
#include <hip/hip_runtime.h>
#include <math.h>

#define NB 4
#define CD 384
#define CM 1536
#define HIDC 128
#define HRES 448
#define NSEG 64
#define PW 34
#define PLANE (PW*PW)
#define PLS 37
#define LNN (CM*1024)

// ---------------- zero scratch ----------------
__global__ void k_zero(float* __restrict__ p, int n) {
  int i = blockIdx.x*256 + threadIdx.x;
  if (i < n) p[i] = 0.f;
}

// ---------------- segment sums + counts ----------------
// grid (CD, NB), 256 threads. Block (b,c): LDS accumulate over 1024 patch
// positions; nearest-neighbor downsample index = seg[b][14*py][14*px].
__global__ void k_seg(const float* __restrict__ fsem, const int* __restrict__ seg,
                      float* __restrict__ sums, float* __restrict__ cnt) {
  __shared__ float ssum[NSEG];
  __shared__ float scnt[NSEG];
  int b = blockIdx.y, c = blockIdx.x, t = threadIdx.x;
  if (t < NSEG) { ssum[t] = 0.f; scnt[t] = 0.f; }
  __syncthreads();
  const float* f = fsem + (b*CD + c)*1024;
  const int* sg = seg + b*HRES*HRES;
  #pragma unroll
  for (int i = 0; i < 4; i++) {
    int p = i*256 + t;
    int py = p >> 5, px = p & 31;
    int id = sg[14*py*HRES + 14*px];
    id = min(max(id, 0), NSEG-1);
    atomicAdd(&ssum[id], f[p]);
    if (c == 0) atomicAdd(&scnt[id], 1.f);
  }
  __syncthreads();
  if (t < NSEG) {
    sums[(b*NSEG + t)*CD + c] = ssum[t];
    if (c == 0) cnt[b*NSEG + t] = scnt[t];
  }
}

// ---------------- avg = sums / cnt (0 if cnt==0) ----------------
__global__ void k_avg(const float* __restrict__ sums, const float* __restrict__ cnt,
                      float* __restrict__ avg) {
  int i = blockIdx.x*256 + threadIdx.x;
  if (i >= NB*NSEG*CD) return;
  float c = cnt[i / CD];
  avg[i] = (c > 0.f) ? sums[i] / c : 0.f;
}

// ---------------- paint + exact bilinear 448->32 + pad ----------------
// sm[b][c][34][34], zero border. Interior: mean of 4 gathered avg vectors.
// grid (34, NB), 256 threads.
__global__ void k_paint(const float* __restrict__ avg, const int* __restrict__ seg,
                        float* __restrict__ sm) {
  int oyp = blockIdx.x;   // padded row 0..33
  int b = blockIdx.y;
  int t = threadIdx.x;
  __shared__ int sid[32][4];
  bool border_row = (oyp == 0 || oyp == 33);
  if (!border_row && t < 32) {
    int oy = oyp - 1;
    const int* sg = seg + b*HRES*HRES;
    int y0 = 14*oy + 6, x0 = 14*t + 6;
    int s00 = sg[y0*HRES + x0],     s01 = sg[y0*HRES + x0 + 1];
    int s10 = sg[(y0+1)*HRES + x0], s11 = sg[(y0+1)*HRES + x0 + 1];
    sid[t][0] = min(max(s00,0),NSEG-1); sid[t][1] = min(max(s01,0),NSEG-1);
    sid[t][2] = min(max(s10,0),NSEG-1); sid[t][3] = min(max(s11,0),NSEG-1);
  }
  __syncthreads();
  const float* av = avg + b*NSEG*CD;
  for (int i = t; i < 34*CD; i += 256) {
    int xp = i % 34;
    int c = i / 34;
    float v = 0.f;
    if (!border_row && xp != 0 && xp != 33) {
      int ox = xp - 1;
      v = 0.25f*(av[sid[ox][0]*CD + c] + av[sid[ox][1]*CD + c]
               + av[sid[ox][2]*CD + c] + av[sid[ox][3]*CD + c]);
    }
    sm[((b*CD + c)*PW + oyp)*PW + xp] = v;
  }
}

// ---------------- conv3x3 384->128 + bias + ReLU (3 convs in one launch) ----
// grid (16, NB, 3). Block: 8 out-channels x 32x32 px. LDS double-buffered
// input plane, stride-37 rows (conflict-free scalar reads).
__global__ __launch_bounds__(256) void k_conv_s(
    const float* __restrict__ sm,
    const float* __restrict__ w0, const float* __restrict__ bs0,
    const float* __restrict__ w1, const float* __restrict__ bs1,
    const float* __restrict__ w2, const float* __restrict__ bs2,
    float* __restrict__ h0, float* __restrict__ h1, float* __restrict__ h2) {
  int og = blockIdx.x, b = blockIdx.y, cid = blockIdx.z;
  const float* w    = (cid == 0) ? w0  : (cid == 1) ? w1  : w2;
  const float* bias = (cid == 0) ? bs0 : (cid == 1) ? bs1 : bs2;
  float* hout       = (cid == 0) ? h0  : (cid == 1) ? h1  : h2;
  int t = threadIdx.x;
  int ty = t >> 3;           // output row 0..31
  int xs = (t & 7) * 4;      // output col start
  __shared__ float pl[2][34*PLS];
  float acc[8][4];
  #pragma unroll
  for (int o = 0; o < 8; o++)
    #pragma unroll
    for (int j = 0; j < 4; j++) acc[o][j] = 0.f;

  {
    const float* src = sm + (b*CD + 0)*PLANE;
    for (int i = t; i < PLANE; i += 256) pl[0][(i/PW)*PLS + (i%PW)] = src[i];
  }
  __syncthreads();
  for (int c = 0; c < CD; c++) {
    int cur = c & 1;
    if (c + 1 < CD) {
      const float* src = sm + (b*CD + c + 1)*PLANE;
      for (int i = t; i < PLANE; i += 256) pl[cur^1][(i/PW)*PLS + (i%PW)] = src[i];
    }
    float in_r[3][6];
    #pragma unroll
    for (int r = 0; r < 3; r++)
      #pragma unroll
      for (int cc = 0; cc < 6; cc++)
        in_r[r][cc] = pl[cur][(ty + r)*PLS + xs + cc];
    #pragma unroll
    for (int o = 0; o < 8; o++) {
      const float* wp = w + ((og*8 + o)*CD + c)*9;
      float w9[9];
      #pragma unroll
      for (int k = 0; k < 9; k++) w9[k] = wp[k];
      #pragma unroll
      for (int j = 0; j < 4; j++) {
        float s = acc[o][j];
        #pragma unroll
        for (int ky = 0; ky < 3; ky++)
          #pragma unroll
          for (int kx = 0; kx < 3; kx++)
            s = fmaf(w9[ky*3+kx], in_r[ky][j+kx], s);
        acc[o][j] = s;
      }
    }
    __syncthreads();
  }
  #pragma unroll
  for (int o = 0; o < 8; o++) {
    int oc = og*8 + o;
    float bv = bias[oc];
    #pragma unroll
    for (int j = 0; j < 4; j++) {
      float v = fmaxf(acc[o][j] + bv, 0.f);
      hout[((b*HIDC + oc)*PW + 1 + ty)*PW + 1 + xs + j] = v;
    }
  }
}

// ---------------- conv3x3 128->1536 + bias (gamma0) ----------------
// grid (192, NB). Same micro-structure; unpadded 32x32 output.
__global__ __launch_bounds__(256) void k_conv_g(
    const float* __restrict__ hin, const float* __restrict__ w,
    const float* __restrict__ bias, float* __restrict__ gout) {
  int og = blockIdx.x, b = blockIdx.y;
  int t = threadIdx.x;
  int ty = t >> 3;
  int xs = (t & 7) * 4;
  __shared__ float pl[2][34*PLS];
  float acc[8][4];
  #pragma unroll
  for (int o = 0; o < 8; o++)
    #pragma unroll
    for (int j = 0; j < 4; j++) acc[o][j] = 0.f;

  {
    const float* src = hin + (b*HIDC + 0)*PLANE;
    for (int i = t; i < PLANE; i += 256) pl[0][(i/PW)*PLS + (i%PW)] = src[i];
  }
  __syncthreads();
  for (int c = 0; c < HIDC; c++) {
    int cur = c & 1;
    if (c + 1 < HIDC) {
      const float* src = hin + (b*HIDC + c + 1)*PLANE;
      for (int i = t; i < PLANE; i += 256) pl[cur^1][(i/PW)*PLS + (i%PW)] = src[i];
    }
    float in_r[3][6];
    #pragma unroll
    for (int r = 0; r < 3; r++)
      #pragma unroll
      for (int cc = 0; cc < 6; cc++)
        in_r[r][cc] = pl[cur][(ty + r)*PLS + xs + cc];
    #pragma unroll
    for (int o = 0; o < 8; o++) {
      const float* wp = w + ((og*8 + o)*HIDC + c)*9;
      float w9[9];
      #pragma unroll
      for (int k = 0; k < 9; k++) w9[k] = wp[k];
      #pragma unroll
      for (int j = 0; j < 4; j++) {
        float s = acc[o][j];
        #pragma unroll
        for (int ky = 0; ky < 3; ky++)
          #pragma unroll
          for (int kx = 0; kx < 3; kx++)
            s = fmaf(w9[ky*3+kx], in_r[ky][j+kx], s);
        acc[o][j] = s;
      }
    }
    __syncthreads();
  }
  #pragma unroll
  for (int o = 0; o < 8; o++) {
    int oc = og*8 + o;
    float bv = bias[oc];
    #pragma unroll
    for (int j = 0; j < 4; j++)
      gout[((b*CM + oc)*32 + ty)*32 + xs + j] = acc[o][j] + bv;
  }
}

// ---------------- LN0 stats (x_main, 1.57M el/sample) ----------------
__global__ void k_ln0(const float* __restrict__ x, float* __restrict__ lnacc) {
  int b = blockIdx.y, t = threadIdx.x;
  const int CHUNK = LNN/32;
  const float* xb = x + b*LNN + blockIdx.x*CHUNK;
  float s = 0.f, q = 0.f;
  for (int i = t; i < CHUNK; i += 256) { float v = xb[i]; s += v; q = fmaf(v, v, q); }
  __shared__ float rs[256], rq[256];
  rs[t] = s; rq[t] = q;
  __syncthreads();
  for (int st = 128; st > 0; st >>= 1) {
    if (t < st) { rs[t] += rs[t+st]; rq[t] += rq[t+st]; }
    __syncthreads();
  }
  if (t == 0) { atomicAdd(&lnacc[b*2], rs[0]); atomicAdd(&lnacc[b*2+1], rq[0]); }
}

// ---------------- small LN stats (single block per sample) ----------------
__global__ void k_ln_small(const float* __restrict__ v, int n, float* __restrict__ mu_r) {
  int b = blockIdx.x, t = threadIdx.x;
  const float* p = v + b*n;
  float s = 0.f, q = 0.f;
  for (int i = t; i < n; i += 256) { float x = p[i]; s += x; q = fmaf(x, x, q); }
  __shared__ float rs[256], rq[256];
  rs[t] = s; rq[t] = q;
  __syncthreads();
  for (int st = 128; st > 0; st >>= 1) {
    if (t < st) { rs[t] += rs[t+st]; rq[t] += rq[t+st]; }
    __syncthreads();
  }
  if (t == 0) {
    float mu = rs[0]/n, var = rq[0]/n - mu*mu;
    mu_r[b*2] = mu; mu_r[b*2+1] = rsqrtf(var + 1e-12f);
  }
}

// ---------------- fold beta conv: wbf = w0 @ wb0, bext = b0 + w0 @ bb0 -----
__global__ void k_fold(const float* __restrict__ w0, const float* __restrict__ wb,
                       const float* __restrict__ bb, const float* __restrict__ b0v,
                       float* __restrict__ wbf, float* __restrict__ bext) {
  int i = blockIdx.x*256 + threadIdx.x;
  if (i < 8*HIDC*9) {
    int o = i / (HIDC*9), jk = i % (HIDC*9);
    float s = 0.f;
    for (int c = 0; c < CM; c++) s = fmaf(w0[o*CM + c], wb[c*HIDC*9 + jk], s);
    wbf[i] = s;
  }
  if (i < 8) {
    float s = b0v[i];
    for (int c = 0; c < CM; c++) s = fmaf(w0[i*CM + c], bb[c], s);
    bext[i] = s;
  }
}

// ---------------- SPADE0 epilogue + conv0(1x1,1536->8) + softplus ----------
// grid (32, NB), 256 threads = 32 px x 8 c-groups (phase1) / 8 o (phase2).
__global__ __launch_bounds__(256) void k_epi0(
    const float* __restrict__ x, const float* __restrict__ gamma0,
    const float* __restrict__ h0, const float* __restrict__ wbf,
    const float* __restrict__ bext, const float* __restrict__ w0,
    const float* __restrict__ lnacc, float* __restrict__ y0) {
  int y = blockIdx.x, b = blockIdx.y;
  int t = threadIdx.x, px = t & 31, g = t >> 5;
  float mu = lnacc[b*2] * (1.f/LNN);
  float var = lnacc[b*2+1] * (1.f/LNN) - mu*mu;
  float r = rsqrtf(var + 1e-12f);
  float acc[8];
  #pragma unroll
  for (int o = 0; o < 8; o++) acc[o] = 0.f;
  const float* xb = x + b*CM*1024 + y*32 + px;
  const float* gb = gamma0 + b*CM*1024 + y*32 + px;
  for (int c = g*(CM/8); c < (g+1)*(CM/8); c++) {
    float xv = xb[c*1024];
    float gm = gb[c*1024];
    float v = (xv - mu)*r*(1.f + gm);
    #pragma unroll
    for (int o = 0; o < 8; o++) acc[o] = fmaf(w0[o*CM + c], v, acc[o]);
  }
  __shared__ float red[8][32][8];
  #pragma unroll
  for (int o = 0; o < 8; o++) red[g][px][o] = acc[o];
  __syncthreads();
  int o = g;
  float s = 0.f;
  #pragma unroll
  for (int gg = 0; gg < 8; gg++) s += red[gg][px][o];
  // collapsed beta branch: conv3x3(h0, wbf)
  const float* hb = h0 + b*HIDC*PLANE + y*PW + px;
  const float* wp0 = wbf + o*HIDC*9;
  float bsum = 0.f;
  for (int j = 0; j < HIDC; j++) {
    const float* hp = hb + j*PLANE;
    const float* wp = wp0 + j*9;
    #pragma unroll
    for (int ky = 0; ky < 3; ky++)
      #pragma unroll
      for (int kx = 0; kx < 3; kx++)
        bsum = fmaf(wp[ky*3+kx], hp[ky*PW + kx], bsum);
  }
  s += bsum + bext[o];
  float sp = fmaxf(s, 0.f) + log1pf(expf(-fabsf(s)));
  y0[(b*8 + o)*1024 + y*32 + px] = sp;
}

// ---------------- SPADE1 epilogue + conv1(1x1,8->16) + softplus ------------
__global__ __launch_bounds__(256) void k_epi1(
    const float* __restrict__ y0, const float* __restrict__ h1,
    const float* __restrict__ wg, const float* __restrict__ bg,
    const float* __restrict__ wb, const float* __restrict__ bb,
    const float* __restrict__ w1, const float* __restrict__ b1v,
    const float* __restrict__ mu_r, float* __restrict__ y1) {
  int y = blockIdx.x, b = blockIdx.y;
  int t = threadIdx.x, px = t & 31, o = t >> 5;  // o < 8
  float mu = mu_r[b*2], r = mu_r[b*2+1];
  const float* hb = h1 + b*HIDC*PLANE + y*PW + px;
  float gs = 0.f, bsv = 0.f;
  for (int j = 0; j < HIDC; j++) {
    const float* hp = hb + j*PLANE;
    const float* wgp = wg + (o*HIDC + j)*9;
    const float* wbp = wb + (o*HIDC + j)*9;
    #pragma unroll
    for (int ky = 0; ky < 3; ky++)
      #pragma unroll
      for (int kx = 0; kx < 3; kx++) {
        float hv = hp[ky*PW + kx];
        gs  = fmaf(wgp[ky*3+kx], hv, gs);
        bsv = fmaf(wbp[ky*3+kx], hv, bsv);
      }
  }
  gs += bg[o]; bsv += bb[o];
  float xv = y0[(b*8 + o)*1024 + y*32 + px];
  float sp = (xv - mu)*r*(1.f + gs) + bsv;
  __shared__ float sl[32][8];
  sl[px][o] = sp;
  __syncthreads();
  #pragma unroll
  for (int q = 0; q < 2; q++) {
    int oc = o + q*8;
    float s = b1v[oc];
    #pragma unroll
    for (int c = 0; c < 8; c++) s = fmaf(w1[oc*8 + c], sl[px][c], s);
    float spv = fmaxf(s, 0.f) + log1pf(expf(-fabsf(s)));
    y1[(b*16 + oc)*1024 + y*32 + px] = spv;
  }
}

// ---------------- SPADE2 epilogue + conv2(1x1,16->1) + softplus ------------
__global__ __launch_bounds__(256) void k_epi2(
    const float* __restrict__ y1, const float* __restrict__ h2,
    const float* __restrict__ wg, const float* __restrict__ bg,
    const float* __restrict__ wb, const float* __restrict__ bb,
    const float* __restrict__ w2, const float* __restrict__ b2v,
    const float* __restrict__ mu_r, float* __restrict__ out) {
  int y = blockIdx.x, b = blockIdx.y;
  int t = threadIdx.x, px = t & 31, q = t >> 5;  // q < 8
  float mu = mu_r[b*2], r = mu_r[b*2+1];
  __shared__ float sl[32][16];
  const float* hb = h2 + b*HIDC*PLANE + y*PW + px;
  #pragma unroll
  for (int qq = 0; qq < 2; qq++) {
    int o = q + qq*8;  // 16 channels
    float gs = 0.f, bsv = 0.f;
    for (int j = 0; j < HIDC; j++) {
      const float* hp = hb + j*PLANE;
      const float* wgp = wg + (o*HIDC + j)*9;
      const float* wbp = wb + (o*HIDC + j)*9;
      #pragma unroll
      for (int ky = 0; ky < 3; ky++)
        #pragma unroll
        for (int kx = 0; kx < 3; kx++) {
          float hv = hp[ky*PW + kx];
          gs  = fmaf(wgp[ky*3+kx], hv, gs);
          bsv = fmaf(wbp[ky*3+kx], hv, bsv);
        }
    }
    gs += bg[o]; bsv += bb[o];
    float xv = y1[(b*16 + o)*1024 + y*32 + px];
    sl[px][o] = (xv - mu)*r*(1.f + gs) + bsv;
  }
  __syncthreads();
  if (t < 32) {
    float s = b2v[0];
    #pragma unroll
    for (int c = 0; c < 16; c++) s = fmaf(w2[c], sl[t][c], s);
    out[b*1024 + y*32 + t] = fmaxf(s, 0.f) + log1pf(expf(-fabsf(s)));
  }
}

extern "C" void kernel_launch(void* const* d_in, const int* in_sizes, int n_in,
                              void* d_out, int out_size, void* d_ws, size_t ws_size,
                              hipStream_t stream) {
  const float* x_main = (const float*)d_in[0];
  const float* f_sem  = (const float*)d_in[1];
  const int*   seg    = (const int*)d_in[2];
  const float* s0_ws = (const float*)d_in[3];
  const float* s0_bs = (const float*)d_in[4];
  const float* s0_wg = (const float*)d_in[5];
  const float* s0_bg = (const float*)d_in[6];
  const float* s0_wb = (const float*)d_in[7];
  const float* s0_bb = (const float*)d_in[8];
  const float* s1_ws = (const float*)d_in[9];
  const float* s1_bs = (const float*)d_in[10];
  const float* s1_wg = (const float*)d_in[11];
  const float* s1_bg = (const float*)d_in[12];
  const float* s1_wb = (const float*)d_in[13];
  const float* s1_bb = (const float*)d_in[14];
  const float* s2_ws = (const float*)d_in[15];
  const float* s2_bs = (const float*)d_in[16];
  const float* s2_wg = (const float*)d_in[17];
  const float* s2_bg = (const float*)d_in[18];
  const float* s2_wb = (const float*)d_in[19];
  const float* s2_bb = (const float*)d_in[20];
  const float* w0 = (const float*)d_in[21];
  const float* b0 = (const float*)d_in[22];
  const float* w1 = (const float*)d_in[23];
  const float* b1 = (const float*)d_in[24];
  const float* w2 = (const float*)d_in[25];
  const float* b2 = (const float*)d_in[26];

  float* ws = (float*)d_ws;
  float* sums  = ws;                         // 98304
  float* cnt   = sums + 98304;               // 256
  float* lnacc = cnt + 256;                  // 8 (+8 pad)
  float* h0    = lnacc + 16;                 // 591872 each
  float* h1    = h0 + 591872;
  float* h2    = h1 + 591872;
  const int ZERO_N = 98304 + 256 + 16 + 3*591872;   // 1874192
  float* avg    = h2 + 591872;               // 98304
  float* smb    = avg + 98304;               // 1775616
  float* gamma0 = smb + 1775616;             // 6291456
  float* wbf    = gamma0 + 6291456;          // 9216
  float* bext   = wbf + 9216;                // 8
  float* mu_r1  = bext + 8;                  // 8
  float* mu_r2  = mu_r1 + 8;                 // 8
  float* y0     = mu_r2 + 8;                 // 32768
  float* y1     = y0 + 32768;                // 65536

  hipLaunchKernelGGL(k_zero, dim3((ZERO_N + 255)/256), dim3(256), 0, stream, ws, ZERO_N);
  hipLaunchKernelGGL(k_seg, dim3(CD, NB), dim3(256), 0, stream, f_sem, seg, sums, cnt);
  hipLaunchKernelGGL(k_avg, dim3((NB*NSEG*CD + 255)/256), dim3(256), 0, stream, sums, cnt, avg);
  hipLaunchKernelGGL(k_paint, dim3(34, NB), dim3(256), 0, stream, avg, seg, smb);
  hipLaunchKernelGGL(k_conv_s, dim3(16, NB, 3), dim3(256), 0, stream,
                     smb, s0_ws, s0_bs, s1_ws, s1_bs, s2_ws, s2_bs, h0, h1, h2);
  hipLaunchKernelGGL(k_ln0, dim3(32, NB), dim3(256), 0, stream, x_main, lnacc);
  hipLaunchKernelGGL(k_fold, dim3(36), dim3(256), 0, stream, w0, s0_wb, s0_bb, b0, wbf, bext);
  hipLaunchKernelGGL(k_conv_g, dim3(192, NB), dim3(256), 0, stream, h0, s0_wg, s0_bg, gamma0);
  hipLaunchKernelGGL(k_epi0, dim3(32, NB), dim3(256), 0, stream,
                     x_main, gamma0, h0, wbf, bext, w0, lnacc, y0);
  hipLaunchKernelGGL(k_ln_small, dim3(NB), dim3(256), 0, stream, y0, 8*1024, mu_r1);
  hipLaunchKernelGGL(k_epi1, dim3(32, NB), dim3(256), 0, stream,
                     y0, h1, s1_wg, s1_bg, s1_wb, s1_bb, w1, b1, mu_r1, y1);
  hipLaunchKernelGGL(k_ln_small, dim3(NB), dim3(256), 0, stream, y1, 16*1024, mu_r2);
  hipLaunchKernelGGL(k_epi2, dim3(32, NB), dim3(256), 0, stream,
                     y1, h2, s2_wg, s2_bg, s2_wb, s2_bb, w2, b2, mu_r2, (float*)d_out);
}

// Round 3
// 422.027 us; speedup vs baseline: 3.2926x; 3.2926x over previous
//
#include <hip/hip_runtime.h>
#include <math.h>

#define NB 4
#define CD 384
#define CM 1536
#define HIDC 128
#define HRES 448
#define NSEG 64
#define LNN (CM*1024)
#define PPX 1156   // 34*34 padded plane
#define LROW 40    // LDS row stride (bf16 elems) = 80B -> <=2-way bank alias

typedef unsigned short bf16_t;
typedef __attribute__((ext_vector_type(8))) short s16x8;
typedef __attribute__((ext_vector_type(4))) float f32x4;

__device__ inline bf16_t f2bf(float v) {
  unsigned int x = __float_as_uint(v);
  unsigned int r = (x + 0x7fffu + ((x >> 16) & 1u)) >> 16;  // RNE, finite inputs
  return (bf16_t)r;
}

// ---------------- zero scratch ----------------
__global__ void k_zero(float* __restrict__ p, int n) {
  int i = blockIdx.x*256 + threadIdx.x;
  if (i < n) p[i] = 0.f;
}

// ---------------- segment sums + counts ----------------
__global__ void k_seg(const float* __restrict__ fsem, const int* __restrict__ seg,
                      float* __restrict__ sums, float* __restrict__ cnt) {
  __shared__ float ssum[NSEG];
  __shared__ float scnt[NSEG];
  int b = blockIdx.y, c = blockIdx.x, t = threadIdx.x;
  if (t < NSEG) { ssum[t] = 0.f; scnt[t] = 0.f; }
  __syncthreads();
  const float* f = fsem + ((size_t)b*CD + c)*1024;
  const int* sg = seg + (size_t)b*HRES*HRES;
  #pragma unroll
  for (int i = 0; i < 4; i++) {
    int p = i*256 + t;
    int py = p >> 5, px = p & 31;
    int id = sg[14*py*HRES + 14*px];
    id = min(max(id, 0), NSEG-1);
    atomicAdd(&ssum[id], f[p]);
    if (c == 0) atomicAdd(&scnt[id], 1.f);
  }
  __syncthreads();
  if (t < NSEG) {
    sums[((size_t)b*NSEG + t)*CD + c] = ssum[t];
    if (c == 0) cnt[b*NSEG + t] = scnt[t];
  }
}

// ---------------- avg = sums / cnt ----------------
__global__ void k_avg(const float* __restrict__ sums, const float* __restrict__ cnt,
                      float* __restrict__ avg) {
  int i = blockIdx.x*256 + threadIdx.x;
  if (i >= NB*NSEG*CD) return;
  float c = cnt[i / CD];
  avg[i] = (c > 0.f) ? sums[i] / c : 0.f;
}

// ---------------- paint + exact bilinear 448->32 -> packed bf16 [b][12][1156][32]
__global__ void k_paint(const float* __restrict__ avg, const int* __restrict__ seg,
                        bf16_t* __restrict__ smP) {
  int oyp = blockIdx.x;   // padded row 0..33
  int b = blockIdx.y;
  int t = threadIdx.x;
  __shared__ int sid[32][4];
  bool border_row = (oyp == 0 || oyp == 33);
  if (!border_row && t < 32) {
    int oy = oyp - 1;
    const int* sg = seg + (size_t)b*HRES*HRES;
    int y0 = 14*oy + 6, x0 = 14*t + 6;
    int s00 = sg[y0*HRES + x0],     s01 = sg[y0*HRES + x0 + 1];
    int s10 = sg[(y0+1)*HRES + x0], s11 = sg[(y0+1)*HRES + x0 + 1];
    sid[t][0] = min(max(s00,0),NSEG-1); sid[t][1] = min(max(s01,0),NSEG-1);
    sid[t][2] = min(max(s10,0),NSEG-1); sid[t][3] = min(max(s11,0),NSEG-1);
  }
  __syncthreads();
  const float* av = avg + (size_t)b*NSEG*CD;
  for (int i = t; i < 34*CD; i += 256) {
    int c = i % CD;
    int xp = i / CD;
    float v = 0.f;
    if (!border_row && xp != 0 && xp != 33) {
      int ox = xp - 1;
      v = 0.25f*(av[sid[ox][0]*CD + c] + av[sid[ox][1]*CD + c]
               + av[sid[ox][2]*CD + c] + av[sid[ox][3]*CD + c]);
    }
    smP[(((size_t)b*12 + (c>>5))*PPX + oyp*34 + xp)*32 + (c&31)] = f2bf(v);
  }
}

// ---------------- fold beta0 conv: wbf = w0 @ wb0, bext = b0 + w0 @ bb0 -----
// K-split grid (36, 4), atomicAdd into zeroed wbf/bext.
__global__ void k_fold2(const float* __restrict__ w0, const float* __restrict__ wb,
                        const float* __restrict__ bb, const float* __restrict__ b0v,
                        float* __restrict__ wbf, float* __restrict__ bext) {
  int i = blockIdx.x*256 + threadIdx.x;
  int ks = blockIdx.y;
  int c0 = ks*(CM/4), c1 = c0 + CM/4;
  if (i < 8*HIDC*9) {
    int o = i / (HIDC*9), jk = i % (HIDC*9);
    float s = 0.f;
    for (int c = c0; c < c1; c++) s = fmaf(w0[o*CM + c], wb[(size_t)c*HIDC*9 + jk], s);
    atomicAdd(&wbf[i], s);
  }
  if (i < 8) {
    float s = (ks == 0) ? b0v[i] : 0.f;
    for (int c = c0; c < c1; c++) s = fmaf(w0[i*CM + c], bb[c], s);
    atomicAdd(&bext[i], s);
  }
}

// ---------------- pack biases ----------------
__global__ void k_makebias(const float* s0bs, const float* s1bs, const float* s2bs,
                           const float* s0bg, const float* s1bg, const float* s1bb,
                           const float* s2bg, const float* s2bb,
                           float* biasS, float* biasG0, float* biasG1, float* biasG2) {
  int t = threadIdx.x;
  for (int i = t; i < 128; i += 256) {
    biasS[i] = s0bs[i]; biasS[128+i] = s1bs[i]; biasS[256+i] = s2bs[i];
  }
  for (int i = t; i < 1664; i += 256) biasG0[i] = (i < 1536) ? s0bg[i] : 0.f;
  if (t < 16) biasG1[t] = (t < 8) ? s1bg[t] : s1bb[t-8];
  if (t < 32) biasG2[t] = (t < 16) ? s2bg[t] : s2bb[t-16];
}

// ---------------- pack conv weights to MFMA A-frag layout (bf16) -----------
// wpk[tap][cb][ob][lane(64)][8]; row o = ob*16+(lane&15), k = cb*32+(lane>>4)*8+j
// two stacked sources [wA(OA rows); wB(OBn rows); zeros]
__global__ void k_packw2(const float* __restrict__ wA, int OA,
                         const float* __restrict__ wB, int OBn,
                         int I, int obTot, int CBn, bf16_t* __restrict__ wpk) {
  size_t idx = (size_t)blockIdx.x*256 + threadIdx.x;
  size_t tot = (size_t)9*CBn*obTot*64;
  if (idx >= tot) return;
  int lane = idx & 63;
  size_t q = idx >> 6;
  int ob = q % obTot; q /= obTot;
  int cb = q % CBn;
  int tap = q / CBn;
  int o = ob*16 + (lane & 15);
  int ib = cb*32 + ((lane >> 4) << 3);
  s16x8 vv;
  #pragma unroll
  for (int j = 0; j < 8; j++) {
    int i = ib + j;
    float v = 0.f;
    if (o < OA) v = wA[((size_t)o*I + i)*9 + tap];
    else if (o - OA < OBn) v = wB[((size_t)(o-OA)*I + i)*9 + tap];
    vv[j] = (short)f2bf(v);
  }
  *(s16x8*)(wpk + idx*8) = vv;
}

// ---------------- MFMA implicit-GEMM conv3x3 ----------------
// MODE0: conv_s  (smP 12cb -> h, bias+ReLU, pack bf16), grid (16,NB,3=cid)
// MODE1: conv_g0 (hP cid0 4cb -> gamma0ext fp32, 1552ch, pad 1664w), grid (16,NB,13=obg)
// MODE2: g1/g2   (hP cid1/2 -> g1out/g2out fp32), grid (16,NB,3): z0=g1, z1/2=g2 ob0/1
template<int MODE>
__global__ __launch_bounds__(256) void k_mconv(
    const bf16_t* __restrict__ inBase,
    const bf16_t* __restrict__ wpk0, const bf16_t* __restrict__ wpk1,
    const float* __restrict__ bias0, const float* __restrict__ bias1,
    float* __restrict__ fout0, float* __restrict__ fout1,
    bf16_t* __restrict__ pout) {
  constexpr int CBn = (MODE == 0) ? 12 : 4;
  constexpr int MF  = (MODE == 2) ? 1 : 8;
  constexpr int WM  = (MODE == 2) ? 1 : 2;
  constexpr int WN  = (MODE == 2) ? 4 : 2;
  constexpr int WMF = MF / WM;
  constexpr int WNF = 4 / WN;
  int strip = blockIdx.x;      // 2-row strip 0..15
  int b = blockIdx.y;
  int z = blockIdx.z;
  int t = threadIdx.x;
  int lane = t & 63, w = t >> 6;
  int wm = w / WN, wn = w % WN;

  const bf16_t* inP; const bf16_t* wpk; const float* bias;
  int obTot, obg;
  if (MODE == 0) {
    inP = inBase;
    wpk = wpk0 + (size_t)z*9*12*8*512;
    bias = bias0 + z*128;
    obTot = 8; obg = 0;
  } else if (MODE == 1) {
    inP = inBase;
    wpk = wpk0; bias = bias0;
    obTot = 104; obg = z;
  } else {
    int cid = (z == 0) ? 1 : 2;
    inP = inBase + (size_t)cid*(NB*4*PPX*32);
    wpk = (z == 0) ? wpk0 : wpk1;
    bias = (z == 0) ? bias0 : bias1;
    obTot = (z == 0) ? 1 : 2;
    obg = (z == 0) ? 0 : z - 1;
  }

  __shared__ bf16_t lds[2][136*LROW];
  const bf16_t* inRegion = inP + ((size_t)b*CBn*PPX + (size_t)strip*68)*32;

  auto stage = [&](int buf, int cb) {
    const bf16_t* src = inRegion + (size_t)cb*PPX*32;
    for (int i = t; i < 136*4; i += 256) {
      int px = i >> 2, g = i & 3;
      *(s16x8*)(&lds[buf][px*LROW + g*8]) = *(const s16x8*)(src + px*32 + g*8);
    }
  };

  f32x4 acc[WMF][WNF];
  #pragma unroll
  for (int mi = 0; mi < WMF; mi++)
    #pragma unroll
    for (int ni = 0; ni < WNF; ni++)
      acc[mi][ni] = (f32x4){0.f, 0.f, 0.f, 0.f};

  stage(0, 0);
  for (int cb = 0; cb < CBn; ++cb) {
    int cur = cb & 1;
    __syncthreads();
    if (cb + 1 < CBn) stage(cur ^ 1, cb + 1);
    #pragma unroll
    for (int tap = 0; tap < 9; ++tap) {
      const int ty = tap / 3, tx = tap % 3;
      s16x8 af[WMF];
      #pragma unroll
      for (int mi = 0; mi < WMF; ++mi) {
        int ob = obg*MF + wm*WMF + mi;
        af[mi] = *(const s16x8*)(wpk + ((((size_t)tap*CBn + cb)*obTot + ob)*64 + lane)*8);
      }
      s16x8 bfv[WNF];
      #pragma unroll
      for (int ni = 0; ni < WNF; ++ni) {
        int pxl = (wn*WNF + ni)*16 + (lane & 15);
        int rpx = ((pxl >> 5) + ty)*34 + (pxl & 31) + tx;
        bfv[ni] = *(const s16x8*)(&lds[cur][rpx*LROW + ((lane >> 4) << 3)]);
      }
      #pragma unroll
      for (int mi = 0; mi < WMF; ++mi)
        #pragma unroll
        for (int ni = 0; ni < WNF; ++ni)
          acc[mi][ni] = __builtin_amdgcn_mfma_f32_16x16x32_bf16(af[mi], bfv[ni], acc[mi][ni], 0, 0, 0);
    }
  }

  #pragma unroll
  for (int mi = 0; mi < WMF; ++mi) {
    int obIdx = obg*MF + wm*WMF + mi;
    #pragma unroll
    for (int ni = 0; ni < WNF; ++ni) {
      int pxl = (wn*WNF + ni)*16 + (lane & 15);
      #pragma unroll
      for (int r = 0; r < 4; ++r) {
        int oc = obIdx*16 + ((lane >> 4) << 2) + r;
        float v = acc[mi][ni][r];
        if (MODE == 0) {
          v = fmaxf(v + bias[oc], 0.f);
          int py = strip*2 + (pxl >> 5) + 1, px = (pxl & 31) + 1;
          pout[(size_t)z*(NB*4*PPX*32) +
               (((size_t)b*4 + (oc >> 5))*PPX + py*34 + px)*32 + (oc & 31)] = f2bf(v);
        } else if (MODE == 1) {
          if (oc < 1552)
            fout0[((size_t)b*1552 + oc)*1024 + strip*64 + pxl] = v + bias[oc];
        } else {
          float* fo = (z == 0) ? fout0 : fout1;
          int Mout = (z == 0) ? 16 : 32;
          fo[((size_t)b*Mout + oc)*1024 + strip*64 + pxl] = v + bias[oc];
        }
      }
    }
  }
}

// ---------------- LN0 stats over x_main ----------------
__global__ void k_ln0(const float* __restrict__ x, float* __restrict__ lnacc) {
  int b = blockIdx.y, t = threadIdx.x;
  const int CHUNK = LNN/64;
  const float4* xb = (const float4*)(x + (size_t)b*LNN + (size_t)blockIdx.x*CHUNK);
  float s = 0.f, q = 0.f;
  for (int i = t; i < CHUNK/4; i += 256) {
    float4 v = xb[i];
    s += v.x + v.y + v.z + v.w;
    q = fmaf(v.x,v.x, fmaf(v.y,v.y, fmaf(v.z,v.z, fmaf(v.w,v.w, q))));
  }
  __shared__ float rs[256], rq[256];
  rs[t] = s; rq[t] = q;
  __syncthreads();
  for (int st = 128; st > 0; st >>= 1) {
    if (t < st) { rs[t] += rs[t+st]; rq[t] += rq[t+st]; }
    __syncthreads();
  }
  if (t == 0) { atomicAdd(&lnacc[b*2], rs[0]); atomicAdd(&lnacc[b*2+1], rq[0]); }
}

// ---------------- small LN stats ----------------
__global__ void k_ln_small(const float* __restrict__ v, int n, float* __restrict__ mu_r) {
  int b = blockIdx.x, t = threadIdx.x;
  const float* p = v + (size_t)b*n;
  float s = 0.f, q = 0.f;
  for (int i = t; i < n; i += 256) { float x = p[i]; s += x; q = fmaf(x, x, q); }
  __shared__ float rs[256], rq[256];
  rs[t] = s; rq[t] = q;
  __syncthreads();
  for (int st = 128; st > 0; st >>= 1) {
    if (t < st) { rs[t] += rs[t+st]; rq[t] += rq[t+st]; }
    __syncthreads();
  }
  if (t == 0) {
    float mu = rs[0]/n, var = rq[0]/n - mu*mu;
    mu_r[b*2] = mu; mu_r[b*2+1] = rsqrtf(var + 1e-12f);
  }
}

// ---------------- SPADE0 partial: sum_c w0[o][c]*xn_c*(1+gamma_c) ----------
// grid (32, NB, 4): 4-way channel split, atomicAdd to y0pre.
__global__ __launch_bounds__(256) void k_epi0p(
    const float* __restrict__ x, const float* __restrict__ g0,
    const float* __restrict__ w0, const float* __restrict__ lnacc,
    float* __restrict__ y0pre) {
  int y = blockIdx.x, b = blockIdx.y, cg = blockIdx.z;
  int t = threadIdx.x, px = t & 31, g8 = t >> 5;
  float mu = lnacc[b*2] * (1.f/LNN);
  float var = lnacc[b*2+1] * (1.f/LNN) - mu*mu;
  float r = rsqrtf(var + 1e-12f);
  float acc[8];
  #pragma unroll
  for (int o = 0; o < 8; o++) acc[o] = 0.f;
  const float* xb = x + (size_t)b*CM*1024 + y*32 + px;
  const float* gb = g0 + (size_t)b*1552*1024 + y*32 + px;
  int c0 = cg*384 + g8*48;
  for (int c = c0; c < c0 + 48; c++) {
    float v = (xb[(size_t)c*1024] - mu)*r*(1.f + gb[(size_t)c*1024]);
    #pragma unroll
    for (int o = 0; o < 8; o++) acc[o] = fmaf(w0[o*CM + c], v, acc[o]);
  }
  __shared__ float red[8][32][8];
  #pragma unroll
  for (int o = 0; o < 8; o++) red[g8][px][o] = acc[o];
  __syncthreads();
  int o = g8;
  float s = 0.f;
  #pragma unroll
  for (int gg = 0; gg < 8; gg++) s += red[gg][px][o];
  atomicAdd(&y0pre[(size_t)b*8192 + o*1024 + y*32 + px], s);
}

// ---------------- finalize y0: + bsum + bext, softplus ----------------
__global__ void k_fin0(const float* __restrict__ y0pre, const float* __restrict__ g0,
                       const float* __restrict__ bext, float* __restrict__ y0) {
  int b = blockIdx.x, t = threadIdx.x;
  for (int i = t; i < 8192; i += 256) {
    int o = i >> 10, px = i & 1023;
    float s = y0pre[(size_t)b*8192 + i]
            + g0[((size_t)b*1552 + 1536 + o)*1024 + px] + bext[o];
    y0[(size_t)b*8192 + i] = fmaxf(s, 0.f) + log1pf(expf(-fabsf(s)));
  }
}

// ---------------- SPADE1 epilogue + conv1(1x1,8->16) + softplus ------------
__global__ __launch_bounds__(256) void k_epi1(
    const float* __restrict__ y0, const float* __restrict__ g1o,
    const float* __restrict__ w1, const float* __restrict__ b1v,
    const float* __restrict__ mu_r, float* __restrict__ y1) {
  int y = blockIdx.x, b = blockIdx.y;
  int t = threadIdx.x, px = t & 31, o = t >> 5;
  float mu = mu_r[b*2], r = mu_r[b*2+1];
  int pg = y*32 + px;
  float gs = g1o[((size_t)b*16 + o)*1024 + pg];
  float bs = g1o[((size_t)b*16 + 8 + o)*1024 + pg];
  float xv = y0[(size_t)b*8192 + o*1024 + pg];
  __shared__ float sl[32][8];
  sl[px][o] = (xv - mu)*r*(1.f + gs) + bs;
  __syncthreads();
  #pragma unroll
  for (int q = 0; q < 2; q++) {
    int oc = o + q*8;
    float s = b1v[oc];
    #pragma unroll
    for (int c = 0; c < 8; c++) s = fmaf(w1[oc*8 + c], sl[px][c], s);
    y1[(size_t)b*16384 + oc*1024 + pg] = fmaxf(s, 0.f) + log1pf(expf(-fabsf(s)));
  }
}

// ---------------- SPADE2 epilogue + conv2(1x1,16->1) + softplus ------------
__global__ __launch_bounds__(256) void k_epi2(
    const float* __restrict__ y1, const float* __restrict__ g2o,
    const float* __restrict__ w2, const float* __restrict__ b2v,
    const float* __restrict__ mu_r, float* __restrict__ out) {
  int y = blockIdx.x, b = blockIdx.y;
  int t = threadIdx.x, px = t & 31, q = t >> 5;
  float mu = mu_r[b*2], r = mu_r[b*2+1];
  int pg = y*32 + px;
  __shared__ float sl[32][16];
  #pragma unroll
  for (int qq = 0; qq < 2; qq++) {
    int o = q + qq*8;
    float gs = g2o[((size_t)b*32 + o)*1024 + pg];
    float bs = g2o[((size_t)b*32 + 16 + o)*1024 + pg];
    float xv = y1[(size_t)b*16384 + o*1024 + pg];
    sl[px][o] = (xv - mu)*r*(1.f + gs) + bs;
  }
  __syncthreads();
  if (t < 32) {
    float s = b2v[0];
    #pragma unroll
    for (int c = 0; c < 16; c++) s = fmaf(w2[c], sl[t][c], s);
    out[(size_t)b*1024 + y*32 + t] = fmaxf(s, 0.f) + log1pf(expf(-fabsf(s)));
  }
}

extern "C" void kernel_launch(void* const* d_in, const int* in_sizes, int n_in,
                              void* d_out, int out_size, void* d_ws, size_t ws_size,
                              hipStream_t stream) {
  const float* x_main = (const float*)d_in[0];
  const float* f_sem  = (const float*)d_in[1];
  const int*   seg    = (const int*)d_in[2];
  const float* s0_ws = (const float*)d_in[3];
  const float* s0_bs = (const float*)d_in[4];
  const float* s0_wg = (const float*)d_in[5];
  const float* s0_bg = (const float*)d_in[6];
  const float* s0_wb = (const float*)d_in[7];
  const float* s0_bb = (const float*)d_in[8];
  const float* s1_ws = (const float*)d_in[9];
  const float* s1_bs = (const float*)d_in[10];
  const float* s1_wg = (const float*)d_in[11];
  const float* s1_bg = (const float*)d_in[12];
  const float* s1_wb = (const float*)d_in[13];
  const float* s1_bb = (const float*)d_in[14];
  const float* s2_ws = (const float*)d_in[15];
  const float* s2_bs = (const float*)d_in[16];
  const float* s2_wg = (const float*)d_in[17];
  const float* s2_bg = (const float*)d_in[18];
  const float* s2_wb = (const float*)d_in[19];
  const float* s2_bb = (const float*)d_in[20];
  const float* w0 = (const float*)d_in[21];
  const float* b0 = (const float*)d_in[22];
  const float* w1 = (const float*)d_in[23];
  const float* b1 = (const float*)d_in[24];
  const float* w2 = (const float*)d_in[25];
  const float* b2 = (const float*)d_in[26];

  float* ws = (float*)d_ws;
  size_t o = 0;
  float* sums  = ws + o; o += 98304;
  float* cnt   = ws + o; o += 256;
  float* lnacc = ws + o; o += 16;
  float* y0pre = ws + o; o += 32768;
  float* wbf   = ws + o; o += 9216;
  float* bext  = ws + o; o += 8;
  bf16_t* hP   = (bf16_t*)(ws + o); o += 887808;   // 3*4*4*1156*32 bf16 (borders need zero)
  const int ZERO_N = (int)o;                        // 1028376
  float* avg    = ws + o; o += 98304;
  bf16_t* smP   = (bf16_t*)(ws + o); o += 887808;  // 4*12*1156*32 bf16
  bf16_t* wpkG0 = (bf16_t*)(ws + o); o += 958464;  // 9*4*104*512 bf16
  bf16_t* wpkG1 = (bf16_t*)(ws + o); o += 9216;
  bf16_t* wpkG2 = (bf16_t*)(ws + o); o += 18432;
  float* biasS  = ws + o; o += 384;
  float* biasG0 = ws + o; o += 1664;
  float* biasG1 = ws + o; o += 16;
  float* biasG2 = ws + o; o += 32;
  float* mu_r1  = ws + o; o += 8;
  float* mu_r2  = ws + o; o += 8;
  float* y0     = ws + o; o += 32768;
  float* y1     = ws + o; o += 65536;
  float* g1out  = ws + o; o += 65536;
  float* g2out  = ws + o; o += 131072;
  // wpkS aliases gamma0ext: wpkS consumed by conv_s before conv_g0 writes gamma0ext
  bf16_t* wpkS     = (bf16_t*)(ws + o);
  float*  gamma0ext = ws + o; o += 6356992;        // 4*1552*1024 fp32

  hipLaunchKernelGGL(k_zero, dim3((ZERO_N + 255)/256), dim3(256), 0, stream, ws, ZERO_N);
  hipLaunchKernelGGL(k_seg, dim3(CD, NB), dim3(256), 0, stream, f_sem, seg, sums, cnt);
  hipLaunchKernelGGL(k_avg, dim3(384), dim3(256), 0, stream, sums, cnt, avg);
  hipLaunchKernelGGL(k_paint, dim3(34, NB), dim3(256), 0, stream, avg, seg, smP);
  hipLaunchKernelGGL(k_fold2, dim3(36, 4), dim3(256), 0, stream, w0, s0_wb, s0_bb, b0, wbf, bext);
  hipLaunchKernelGGL(k_makebias, dim3(1), dim3(256), 0, stream,
                     s0_bs, s1_bs, s2_bs, s0_bg, s1_bg, s1_bb, s2_bg, s2_bb,
                     biasS, biasG0, biasG1, biasG2);
  // pack weights
  hipLaunchKernelGGL(k_packw2, dim3(216), dim3(256), 0, stream,
                     s0_ws, 128, (const float*)nullptr, 0, 384, 8, 12, wpkS);
  hipLaunchKernelGGL(k_packw2, dim3(216), dim3(256), 0, stream,
                     s1_ws, 128, (const float*)nullptr, 0, 384, 8, 12, wpkS + 442368);
  hipLaunchKernelGGL(k_packw2, dim3(216), dim3(256), 0, stream,
                     s2_ws, 128, (const float*)nullptr, 0, 384, 8, 12, wpkS + 884736);
  hipLaunchKernelGGL(k_packw2, dim3(936), dim3(256), 0, stream,
                     s0_wg, 1536, wbf, 8, 128, 104, 4, wpkG0);
  hipLaunchKernelGGL(k_packw2, dim3(9), dim3(256), 0, stream,
                     s1_wg, 8, s1_wb, 8, 128, 1, 4, wpkG1);
  hipLaunchKernelGGL(k_packw2, dim3(18), dim3(256), 0, stream,
                     s2_wg, 16, s2_wb, 16, 128, 2, 4, wpkG2);
  // convs (MFMA)
  hipLaunchKernelGGL((k_mconv<0>), dim3(16, NB, 3), dim3(256), 0, stream,
                     smP, wpkS, (const bf16_t*)nullptr, biasS, (const float*)nullptr,
                     (float*)nullptr, (float*)nullptr, hP);
  hipLaunchKernelGGL((k_mconv<1>), dim3(16, NB, 13), dim3(256), 0, stream,
                     hP, wpkG0, (const bf16_t*)nullptr, biasG0, (const float*)nullptr,
                     gamma0ext, (float*)nullptr, (bf16_t*)nullptr);
  hipLaunchKernelGGL((k_mconv<2>), dim3(16, NB, 3), dim3(256), 0, stream,
                     hP, wpkG1, wpkG2, biasG1, biasG2, g1out, g2out, (bf16_t*)nullptr);
  // epilogues
  hipLaunchKernelGGL(k_ln0, dim3(64, NB), dim3(256), 0, stream, x_main, lnacc);
  hipLaunchKernelGGL(k_epi0p, dim3(32, NB, 4), dim3(256), 0, stream,
                     x_main, gamma0ext, w0, lnacc, y0pre);
  hipLaunchKernelGGL(k_fin0, dim3(NB), dim3(256), 0, stream, y0pre, gamma0ext, bext, y0);
  hipLaunchKernelGGL(k_ln_small, dim3(NB), dim3(256), 0, stream, y0, 8192, mu_r1);
  hipLaunchKernelGGL(k_epi1, dim3(32, NB), dim3(256), 0, stream, y0, g1out, w1, b1, mu_r1, y1);
  hipLaunchKernelGGL(k_ln_small, dim3(NB), dim3(256), 0, stream, y1, 16384, mu_r2);
  hipLaunchKernelGGL(k_epi2, dim3(32, NB), dim3(256), 0, stream, y1, g2out, w2, b2, mu_r2, (float*)d_out);
}

// Round 4
// 316.291 us; speedup vs baseline: 4.3933x; 1.3343x over previous
//
#include <hip/hip_runtime.h>
#include <math.h>

#define NB 4
#define CD 384
#define CM 1536
#define HIDC 128
#define HRES 448
#define NSEG 64
#define LNN (CM*1024)
#define PPX 1156   // 34*34 padded plane
#define LROW 40    // LDS row stride (bf16 elems) = 80B -> <=2-way bank alias

typedef unsigned short bf16_t;
typedef __attribute__((ext_vector_type(8))) short s16x8;
typedef __attribute__((ext_vector_type(4))) float f32x4;

__device__ inline bf16_t f2bf(float v) {
  unsigned int x = __float_as_uint(v);
  unsigned int r = (x + 0x7fffu + ((x >> 16) & 1u)) >> 16;  // RNE, finite inputs
  return (bf16_t)r;
}

// ---------------- zero scratch ----------------
__global__ void k_zero(float* __restrict__ p, int n) {
  int i = blockIdx.x*256 + threadIdx.x;
  if (i < n) p[i] = 0.f;
}

// ---------------- segment sums + counts ----------------
__global__ void k_seg(const float* __restrict__ fsem, const int* __restrict__ seg,
                      float* __restrict__ sums, float* __restrict__ cnt) {
  __shared__ float ssum[NSEG];
  __shared__ float scnt[NSEG];
  int b = blockIdx.y, c = blockIdx.x, t = threadIdx.x;
  if (t < NSEG) { ssum[t] = 0.f; scnt[t] = 0.f; }
  __syncthreads();
  const float* f = fsem + ((size_t)b*CD + c)*1024;
  const int* sg = seg + (size_t)b*HRES*HRES;
  #pragma unroll
  for (int i = 0; i < 4; i++) {
    int p = i*256 + t;
    int py = p >> 5, px = p & 31;
    int id = sg[14*py*HRES + 14*px];
    id = min(max(id, 0), NSEG-1);
    atomicAdd(&ssum[id], f[p]);
    if (c == 0) atomicAdd(&scnt[id], 1.f);
  }
  __syncthreads();
  if (t < NSEG) {
    sums[((size_t)b*NSEG + t)*CD + c] = ssum[t];
    if (c == 0) cnt[b*NSEG + t] = scnt[t];
  }
}

// ---------------- avg = sums / cnt ----------------
__global__ void k_avg(const float* __restrict__ sums, const float* __restrict__ cnt,
                      float* __restrict__ avg) {
  int i = blockIdx.x*256 + threadIdx.x;
  if (i >= NB*NSEG*CD) return;
  float c = cnt[i / CD];
  avg[i] = (c > 0.f) ? sums[i] / c : 0.f;
}

// ---------------- paint + exact bilinear 448->32 -> packed bf16 [b][12][1156][32]
__global__ void k_paint(const float* __restrict__ avg, const int* __restrict__ seg,
                        bf16_t* __restrict__ smP) {
  int oyp = blockIdx.x;   // padded row 0..33
  int b = blockIdx.y;
  int t = threadIdx.x;
  __shared__ int sid[32][4];
  bool border_row = (oyp == 0 || oyp == 33);
  if (!border_row && t < 32) {
    int oy = oyp - 1;
    const int* sg = seg + (size_t)b*HRES*HRES;
    int y0 = 14*oy + 6, x0 = 14*t + 6;
    int s00 = sg[y0*HRES + x0],     s01 = sg[y0*HRES + x0 + 1];
    int s10 = sg[(y0+1)*HRES + x0], s11 = sg[(y0+1)*HRES + x0 + 1];
    sid[t][0] = min(max(s00,0),NSEG-1); sid[t][1] = min(max(s01,0),NSEG-1);
    sid[t][2] = min(max(s10,0),NSEG-1); sid[t][3] = min(max(s11,0),NSEG-1);
  }
  __syncthreads();
  const float* av = avg + (size_t)b*NSEG*CD;
  for (int i = t; i < 34*CD; i += 256) {
    int c = i % CD;
    int xp = i / CD;
    float v = 0.f;
    if (!border_row && xp != 0 && xp != 33) {
      int ox = xp - 1;
      v = 0.25f*(av[sid[ox][0]*CD + c] + av[sid[ox][1]*CD + c]
               + av[sid[ox][2]*CD + c] + av[sid[ox][3]*CD + c]);
    }
    smP[(((size_t)b*12 + (c>>5))*PPX + oyp*34 + xp)*32 + (c&31)] = f2bf(v);
  }
}

// ---------------- fold beta0: wbf = w0 @ wb0 (coalesced K-split GEMM) ------
// grid (6, 32): bx<5 -> 256-wide N-slices, bx==5 -> bext. K-chunk = 48 rows.
__global__ void k_fold3(const float* __restrict__ w0, const float* __restrict__ wb,
                        const float* __restrict__ bb, const float* __restrict__ b0v,
                        float* __restrict__ wbf, float* __restrict__ bext) {
  int bx = blockIdx.x, ks = blockIdx.y, t = threadIdx.x;
  int c0 = ks*48;
  if (bx < 5) {
    int jk = bx*256 + t;
    if (jk >= 1152) return;
    float acc[8];
    #pragma unroll
    for (int o = 0; o < 8; o++) acc[o] = 0.f;
    for (int c = c0; c < c0 + 48; c++) {
      float wv = wb[(size_t)c*1152 + jk];      // coalesced across lanes
      #pragma unroll
      for (int o = 0; o < 8; o++) acc[o] = fmaf(w0[o*CM + c], wv, acc[o]);  // uniform -> sgpr
    }
    #pragma unroll
    for (int o = 0; o < 8; o++) atomicAdd(&wbf[o*1152 + jk], acc[o]);
  } else {
    if (t < 8) {
      float s = (ks == 0) ? b0v[t] : 0.f;
      for (int c = c0; c < c0 + 48; c++) s = fmaf(w0[t*CM + c], bb[c], s);
      atomicAdd(&bext[t], s);
    }
  }
}

// ---------------- pack biases ----------------
__global__ void k_makebias(const float* s0bs, const float* s1bs, const float* s2bs,
                           const float* s0bg, const float* s1bg, const float* s1bb,
                           const float* s2bg, const float* s2bb,
                           float* biasS, float* biasG0, float* biasG1, float* biasG2) {
  int t = threadIdx.x;
  for (int i = t; i < 128; i += 256) {
    biasS[i] = s0bs[i]; biasS[128+i] = s1bs[i]; biasS[256+i] = s2bs[i];
  }
  for (int i = t; i < 1664; i += 256) biasG0[i] = (i < 1536) ? s0bg[i] : 0.f;
  if (t < 16) biasG1[t] = (t < 8) ? s1bg[t] : s1bb[t-8];
  if (t < 32) biasG2[t] = (t < 16) ? s2bg[t] : s2bb[t-16];
}

// ---------------- pack conv weights to MFMA A-frag layout (bf16) -----------
// wpk[tap][cb][ob][lane(64)][8]; row o = ob*16+(lane&15), k = cb*32+(lane>>4)*8+j
// two stacked sources [wA(OA rows); wB(OBn rows); zeros]
__global__ void k_packw2(const float* __restrict__ wA, int OA,
                         const float* __restrict__ wB, int OBn,
                         int I, int obTot, int CBn, bf16_t* __restrict__ wpk) {
  size_t idx = (size_t)blockIdx.x*256 + threadIdx.x;
  size_t tot = (size_t)9*CBn*obTot*64;
  if (idx >= tot) return;
  int lane = idx & 63;
  size_t q = idx >> 6;
  int ob = q % obTot; q /= obTot;
  int cb = q % CBn;
  int tap = q / CBn;
  int o = ob*16 + (lane & 15);
  int ib = cb*32 + ((lane >> 4) << 3);
  s16x8 vv;
  #pragma unroll
  for (int j = 0; j < 8; j++) {
    int i = ib + j;
    float v = 0.f;
    if (o < OA) v = wA[((size_t)o*I + i)*9 + tap];
    else if (o - OA < OBn) v = wB[((size_t)(o-OA)*I + i)*9 + tap];
    vv[j] = (short)f2bf(v);
  }
  *(s16x8*)(wpk + idx*8) = vv;
}

// ---------------- MFMA implicit-GEMM conv3x3 ----------------
// MODE0: conv_s  (smP 12cb -> h, bias+ReLU, pack bf16), grid (16,NB,3=cid)
// MODE1: conv_g0 (hP cid0 4cb -> gamma0ext fp32, 1552ch, pad 1664w), grid (16,NB,13=obg)
// MODE2: g1/g2   (hP cid1/2 -> g1out/g2out fp32), grid (16,NB,3): z0=g1, z1/2=g2 ob0/1
template<int MODE>
__global__ __launch_bounds__(256) void k_mconv(
    const bf16_t* __restrict__ inBase,
    const bf16_t* __restrict__ wpk0, const bf16_t* __restrict__ wpk1,
    const float* __restrict__ bias0, const float* __restrict__ bias1,
    float* __restrict__ fout0, float* __restrict__ fout1,
    bf16_t* __restrict__ pout) {
  constexpr int CBn = (MODE == 0) ? 12 : 4;
  constexpr int MF  = (MODE == 2) ? 1 : 8;
  constexpr int WM  = (MODE == 2) ? 1 : 2;
  constexpr int WN  = (MODE == 2) ? 4 : 2;
  constexpr int WMF = MF / WM;
  constexpr int WNF = 4 / WN;
  int strip = blockIdx.x;      // 2-row strip 0..15
  int b = blockIdx.y;
  int z = blockIdx.z;
  int t = threadIdx.x;
  int lane = t & 63, w = t >> 6;
  int wm = w / WN, wn = w % WN;

  const bf16_t* inP; const bf16_t* wpk; const float* bias;
  int obTot, obg;
  if (MODE == 0) {
    inP = inBase;
    wpk = wpk0 + (size_t)z*9*12*8*512;
    bias = bias0 + z*128;
    obTot = 8; obg = 0;
  } else if (MODE == 1) {
    inP = inBase;
    wpk = wpk0; bias = bias0;
    obTot = 104; obg = z;
  } else {
    int cid = (z == 0) ? 1 : 2;
    inP = inBase + (size_t)cid*(NB*4*PPX*32);
    wpk = (z == 0) ? wpk0 : wpk1;
    bias = (z == 0) ? bias0 : bias1;
    obTot = (z == 0) ? 1 : 2;
    obg = (z == 0) ? 0 : z - 1;
  }

  __shared__ bf16_t lds[2][136*LROW];
  const bf16_t* inRegion = inP + ((size_t)b*CBn*PPX + (size_t)strip*68)*32;

  auto stage = [&](int buf, int cb) {
    const bf16_t* src = inRegion + (size_t)cb*PPX*32;
    for (int i = t; i < 136*4; i += 256) {
      int px = i >> 2, g = i & 3;
      *(s16x8*)(&lds[buf][px*LROW + g*8]) = *(const s16x8*)(src + px*32 + g*8);
    }
  };

  f32x4 acc[WMF][WNF];
  #pragma unroll
  for (int mi = 0; mi < WMF; mi++)
    #pragma unroll
    for (int ni = 0; ni < WNF; ni++)
      acc[mi][ni] = (f32x4){0.f, 0.f, 0.f, 0.f};

  stage(0, 0);
  for (int cb = 0; cb < CBn; ++cb) {
    int cur = cb & 1;
    __syncthreads();
    if (cb + 1 < CBn) stage(cur ^ 1, cb + 1);
    #pragma unroll
    for (int tap = 0; tap < 9; ++tap) {
      const int ty = tap / 3, tx = tap % 3;
      s16x8 af[WMF];
      #pragma unroll
      for (int mi = 0; mi < WMF; ++mi) {
        int ob = obg*MF + wm*WMF + mi;
        af[mi] = *(const s16x8*)(wpk + ((((size_t)tap*CBn + cb)*obTot + ob)*64 + lane)*8);
      }
      s16x8 bfv[WNF];
      #pragma unroll
      for (int ni = 0; ni < WNF; ++ni) {
        int pxl = (wn*WNF + ni)*16 + (lane & 15);
        int rpx = ((pxl >> 5) + ty)*34 + (pxl & 31) + tx;
        bfv[ni] = *(const s16x8*)(&lds[cur][rpx*LROW + ((lane >> 4) << 3)]);
      }
      #pragma unroll
      for (int mi = 0; mi < WMF; ++mi)
        #pragma unroll
        for (int ni = 0; ni < WNF; ++ni)
          acc[mi][ni] = __builtin_amdgcn_mfma_f32_16x16x32_bf16(af[mi], bfv[ni], acc[mi][ni], 0, 0, 0);
    }
  }

  #pragma unroll
  for (int mi = 0; mi < WMF; ++mi) {
    int obIdx = obg*MF + wm*WMF + mi;
    #pragma unroll
    for (int ni = 0; ni < WNF; ++ni) {
      int pxl = (wn*WNF + ni)*16 + (lane & 15);
      #pragma unroll
      for (int r = 0; r < 4; ++r) {
        int oc = obIdx*16 + ((lane >> 4) << 2) + r;
        float v = acc[mi][ni][r];
        if (MODE == 0) {
          v = fmaxf(v + bias[oc], 0.f);
          int py = strip*2 + (pxl >> 5) + 1, px = (pxl & 31) + 1;
          pout[(size_t)z*(NB*4*PPX*32) +
               (((size_t)b*4 + (oc >> 5))*PPX + py*34 + px)*32 + (oc & 31)] = f2bf(v);
        } else if (MODE == 1) {
          if (oc < 1552)
            fout0[((size_t)b*1552 + oc)*1024 + strip*64 + pxl] = v + bias[oc];
        } else {
          float* fo = (z == 0) ? fout0 : fout1;
          int Mout = (z == 0) ? 16 : 32;
          fo[((size_t)b*Mout + oc)*1024 + strip*64 + pxl] = v + bias[oc];
        }
      }
    }
  }
}

// ---------------- LN0 stats over x_main ----------------
__global__ void k_ln0(const float* __restrict__ x, float* __restrict__ lnacc) {
  int b = blockIdx.y, t = threadIdx.x;
  const int CHUNK = LNN/64;
  const float4* xb = (const float4*)(x + (size_t)b*LNN + (size_t)blockIdx.x*CHUNK);
  float s = 0.f, q = 0.f;
  for (int i = t; i < CHUNK/4; i += 256) {
    float4 v = xb[i];
    s += v.x + v.y + v.z + v.w;
    q = fmaf(v.x,v.x, fmaf(v.y,v.y, fmaf(v.z,v.z, fmaf(v.w,v.w, q))));
  }
  __shared__ float rs[256], rq[256];
  rs[t] = s; rq[t] = q;
  __syncthreads();
  for (int st = 128; st > 0; st >>= 1) {
    if (t < st) { rs[t] += rs[t+st]; rq[t] += rq[t+st]; }
    __syncthreads();
  }
  if (t == 0) { atomicAdd(&lnacc[b*2], rs[0]); atomicAdd(&lnacc[b*2+1], rq[0]); }
}

// ---------------- small LN stats ----------------
__global__ void k_ln_small(const float* __restrict__ v, int n, float* __restrict__ mu_r) {
  int b = blockIdx.x, t = threadIdx.x;
  const float* p = v + (size_t)b*n;
  float s = 0.f, q = 0.f;
  for (int i = t; i < n; i += 256) { float x = p[i]; s += x; q = fmaf(x, x, q); }
  __shared__ float rs[256], rq[256];
  rs[t] = s; rq[t] = q;
  __syncthreads();
  for (int st = 128; st > 0; st >>= 1) {
    if (t < st) { rs[t] += rs[t+st]; rq[t] += rq[t+st]; }
    __syncthreads();
  }
  if (t == 0) {
    float mu = rs[0]/n, var = rq[0]/n - mu*mu;
    mu_r[b*2] = mu; mu_r[b*2+1] = rsqrtf(var + 1e-12f);
  }
}

// ---------------- SPADE0 partial: sum_c w0[o][c]*xn_c*(1+gamma_c) ----------
// grid (32, NB, 4): 4-way channel split, atomicAdd to y0pre.
__global__ __launch_bounds__(256) void k_epi0p(
    const float* __restrict__ x, const float* __restrict__ g0,
    const float* __restrict__ w0, const float* __restrict__ lnacc,
    float* __restrict__ y0pre) {
  int y = blockIdx.x, b = blockIdx.y, cg = blockIdx.z;
  int t = threadIdx.x, px = t & 31, g8 = t >> 5;
  float mu = lnacc[b*2] * (1.f/LNN);
  float var = lnacc[b*2+1] * (1.f/LNN) - mu*mu;
  float r = rsqrtf(var + 1e-12f);
  float acc[8];
  #pragma unroll
  for (int o = 0; o < 8; o++) acc[o] = 0.f;
  const float* xb = x + (size_t)b*CM*1024 + y*32 + px;
  const float* gb = g0 + (size_t)b*1552*1024 + y*32 + px;
  int c0 = cg*384 + g8*48;
  for (int c = c0; c < c0 + 48; c++) {
    float v = (xb[(size_t)c*1024] - mu)*r*(1.f + gb[(size_t)c*1024]);
    #pragma unroll
    for (int o = 0; o < 8; o++) acc[o] = fmaf(w0[o*CM + c], v, acc[o]);
  }
  __shared__ float red[8][32][8];
  #pragma unroll
  for (int o = 0; o < 8; o++) red[g8][px][o] = acc[o];
  __syncthreads();
  int o = g8;
  float s = 0.f;
  #pragma unroll
  for (int gg = 0; gg < 8; gg++) s += red[gg][px][o];
  atomicAdd(&y0pre[(size_t)b*8192 + o*1024 + y*32 + px], s);
}

// ---------------- finalize y0: + bsum + bext, softplus ----------------
__global__ void k_fin0(const float* __restrict__ y0pre, const float* __restrict__ g0,
                       const float* __restrict__ bext, float* __restrict__ y0) {
  int b = blockIdx.x, t = threadIdx.x;
  for (int i = t; i < 8192; i += 256) {
    int o = i >> 10, px = i & 1023;
    float s = y0pre[(size_t)b*8192 + i]
            + g0[((size_t)b*1552 + 1536 + o)*1024 + px] + bext[o];
    y0[(size_t)b*8192 + i] = fmaxf(s, 0.f) + log1pf(expf(-fabsf(s)));
  }
}

// ---------------- SPADE1 epilogue + conv1(1x1,8->16) + softplus ------------
__global__ __launch_bounds__(256) void k_epi1(
    const float* __restrict__ y0, const float* __restrict__ g1o,
    const float* __restrict__ w1, const float* __restrict__ b1v,
    const float* __restrict__ mu_r, float* __restrict__ y1) {
  int y = blockIdx.x, b = blockIdx.y;
  int t = threadIdx.x, px = t & 31, o = t >> 5;
  float mu = mu_r[b*2], r = mu_r[b*2+1];
  int pg = y*32 + px;
  float gs = g1o[((size_t)b*16 + o)*1024 + pg];
  float bs = g1o[((size_t)b*16 + 8 + o)*1024 + pg];
  float xv = y0[(size_t)b*8192 + o*1024 + pg];
  __shared__ float sl[32][8];
  sl[px][o] = (xv - mu)*r*(1.f + gs) + bs;
  __syncthreads();
  #pragma unroll
  for (int q = 0; q < 2; q++) {
    int oc = o + q*8;
    float s = b1v[oc];
    #pragma unroll
    for (int c = 0; c < 8; c++) s = fmaf(w1[oc*8 + c], sl[px][c], s);
    y1[(size_t)b*16384 + oc*1024 + pg] = fmaxf(s, 0.f) + log1pf(expf(-fabsf(s)));
  }
}

// ---------------- SPADE2 epilogue + conv2(1x1,16->1) + softplus ------------
__global__ __launch_bounds__(256) void k_epi2(
    const float* __restrict__ y1, const float* __restrict__ g2o,
    const float* __restrict__ w2, const float* __restrict__ b2v,
    const float* __restrict__ mu_r, float* __restrict__ out) {
  int y = blockIdx.x, b = blockIdx.y;
  int t = threadIdx.x, px = t & 31, q = t >> 5;
  float mu = mu_r[b*2], r = mu_r[b*2+1];
  int pg = y*32 + px;
  __shared__ float sl[32][16];
  #pragma unroll
  for (int qq = 0; qq < 2; qq++) {
    int o = q + qq*8;
    float gs = g2o[((size_t)b*32 + o)*1024 + pg];
    float bs = g2o[((size_t)b*32 + 16 + o)*1024 + pg];
    float xv = y1[(size_t)b*16384 + o*1024 + pg];
    sl[px][o] = (xv - mu)*r*(1.f + gs) + bs;
  }
  __syncthreads();
  if (t < 32) {
    float s = b2v[0];
    #pragma unroll
    for (int c = 0; c < 16; c++) s = fmaf(w2[c], sl[t][c], s);
    out[(size_t)b*1024 + y*32 + t] = fmaxf(s, 0.f) + log1pf(expf(-fabsf(s)));
  }
}

extern "C" void kernel_launch(void* const* d_in, const int* in_sizes, int n_in,
                              void* d_out, int out_size, void* d_ws, size_t ws_size,
                              hipStream_t stream) {
  const float* x_main = (const float*)d_in[0];
  const float* f_sem  = (const float*)d_in[1];
  const int*   seg    = (const int*)d_in[2];
  const float* s0_ws = (const float*)d_in[3];
  const float* s0_bs = (const float*)d_in[4];
  const float* s0_wg = (const float*)d_in[5];
  const float* s0_bg = (const float*)d_in[6];
  const float* s0_wb = (const float*)d_in[7];
  const float* s0_bb = (const float*)d_in[8];
  const float* s1_ws = (const float*)d_in[9];
  const float* s1_bs = (const float*)d_in[10];
  const float* s1_wg = (const float*)d_in[11];
  const float* s1_bg = (const float*)d_in[12];
  const float* s1_wb = (const float*)d_in[13];
  const float* s1_bb = (const float*)d_in[14];
  const float* s2_ws = (const float*)d_in[15];
  const float* s2_bs = (const float*)d_in[16];
  const float* s2_wg = (const float*)d_in[17];
  const float* s2_bg = (const float*)d_in[18];
  const float* s2_wb = (const float*)d_in[19];
  const float* s2_bb = (const float*)d_in[20];
  const float* w0 = (const float*)d_in[21];
  const float* b0 = (const float*)d_in[22];
  const float* w1 = (const float*)d_in[23];
  const float* b1 = (const float*)d_in[24];
  const float* w2 = (const float*)d_in[25];
  const float* b2 = (const float*)d_in[26];

  float* ws = (float*)d_ws;
  size_t o = 0;
  float* sums  = ws + o; o += 98304;
  float* cnt   = ws + o; o += 256;
  float* lnacc = ws + o; o += 16;
  float* y0pre = ws + o; o += 32768;
  float* wbf   = ws + o; o += 9216;
  float* bext  = ws + o; o += 8;
  bf16_t* hP   = (bf16_t*)(ws + o); o += 887808;   // 3*4*4*1156*32 bf16 (borders need zero)
  const int ZERO_N = (int)o;                        // 1028376
  float* avg    = ws + o; o += 98304;
  bf16_t* smP   = (bf16_t*)(ws + o); o += 887808;  // 4*12*1156*32 bf16
  bf16_t* wpkG0 = (bf16_t*)(ws + o); o += 958464;  // 9*4*104*512 bf16
  bf16_t* wpkG1 = (bf16_t*)(ws + o); o += 9216;
  bf16_t* wpkG2 = (bf16_t*)(ws + o); o += 18432;
  float* biasS  = ws + o; o += 384;
  float* biasG0 = ws + o; o += 1664;
  float* biasG1 = ws + o; o += 16;
  float* biasG2 = ws + o; o += 32;
  float* mu_r1  = ws + o; o += 8;
  float* mu_r2  = ws + o; o += 8;
  float* y0     = ws + o; o += 32768;
  float* y1     = ws + o; o += 65536;
  float* g1out  = ws + o; o += 65536;
  float* g2out  = ws + o; o += 131072;
  // wpkS aliases gamma0ext: wpkS consumed by conv_s before conv_g0 writes gamma0ext
  bf16_t* wpkS     = (bf16_t*)(ws + o);
  float*  gamma0ext = ws + o; o += 6356992;        // 4*1552*1024 fp32

  hipLaunchKernelGGL(k_zero, dim3((ZERO_N + 255)/256), dim3(256), 0, stream, ws, ZERO_N);
  hipLaunchKernelGGL(k_seg, dim3(CD, NB), dim3(256), 0, stream, f_sem, seg, sums, cnt);
  hipLaunchKernelGGL(k_avg, dim3(384), dim3(256), 0, stream, sums, cnt, avg);
  hipLaunchKernelGGL(k_paint, dim3(34, NB), dim3(256), 0, stream, avg, seg, smP);
  hipLaunchKernelGGL(k_fold3, dim3(6, 32), dim3(256), 0, stream, w0, s0_wb, s0_bb, b0, wbf, bext);
  hipLaunchKernelGGL(k_makebias, dim3(1), dim3(256), 0, stream,
                     s0_bs, s1_bs, s2_bs, s0_bg, s1_bg, s1_bb, s2_bg, s2_bb,
                     biasS, biasG0, biasG1, biasG2);
  // pack weights
  hipLaunchKernelGGL(k_packw2, dim3(216), dim3(256), 0, stream,
                     s0_ws, 128, (const float*)nullptr, 0, 384, 8, 12, wpkS);
  hipLaunchKernelGGL(k_packw2, dim3(216), dim3(256), 0, stream,
                     s1_ws, 128, (const float*)nullptr, 0, 384, 8, 12, wpkS + 442368);
  hipLaunchKernelGGL(k_packw2, dim3(216), dim3(256), 0, stream,
                     s2_ws, 128, (const float*)nullptr, 0, 384, 8, 12, wpkS + 884736);
  hipLaunchKernelGGL(k_packw2, dim3(936), dim3(256), 0, stream,
                     s0_wg, 1536, wbf, 8, 128, 104, 4, wpkG0);
  hipLaunchKernelGGL(k_packw2, dim3(9), dim3(256), 0, stream,
                     s1_wg, 8, s1_wb, 8, 128, 1, 4, wpkG1);
  hipLaunchKernelGGL(k_packw2, dim3(18), dim3(256), 0, stream,
                     s2_wg, 16, s2_wb, 16, 128, 2, 4, wpkG2);
  // convs (MFMA)
  hipLaunchKernelGGL((k_mconv<0>), dim3(16, NB, 3), dim3(256), 0, stream,
                     smP, wpkS, (const bf16_t*)nullptr, biasS, (const float*)nullptr,
                     (float*)nullptr, (float*)nullptr, hP);
  hipLaunchKernelGGL((k_mconv<1>), dim3(16, NB, 13), dim3(256), 0, stream,
                     hP, wpkG0, (const bf16_t*)nullptr, biasG0, (const float*)nullptr,
                     gamma0ext, (float*)nullptr, (bf16_t*)nullptr);
  hipLaunchKernelGGL((k_mconv<2>), dim3(16, NB, 3), dim3(256), 0, stream,
                     hP, wpkG1, wpkG2, biasG1, biasG2, g1out, g2out, (bf16_t*)nullptr);
  // epilogues
  hipLaunchKernelGGL(k_ln0, dim3(64, NB), dim3(256), 0, stream, x_main, lnacc);
  hipLaunchKernelGGL(k_epi0p, dim3(32, NB, 4), dim3(256), 0, stream,
                     x_main, gamma0ext, w0, lnacc, y0pre);
  hipLaunchKernelGGL(k_fin0, dim3(NB), dim3(256), 0, stream, y0pre, gamma0ext, bext, y0);
  hipLaunchKernelGGL(k_ln_small, dim3(NB), dim3(256), 0, stream, y0, 8192, mu_r1);
  hipLaunchKernelGGL(k_epi1, dim3(32, NB), dim3(256), 0, stream, y0, g1out, w1, b1, mu_r1, y1);
  hipLaunchKernelGGL(k_ln_small, dim3(NB), dim3(256), 0, stream, y1, 16384, mu_r2);
  hipLaunchKernelGGL(k_epi2, dim3(32, NB), dim3(256), 0, stream, y1, g2out, w2, b2, mu_r2, (float*)d_out);
}